// Round 1
// baseline (111.015 us; speedup 1.0000x reference)
//
#include <hip/hip_runtime.h>

#define NROWS 256
#define MCOLS 256

__global__ __launch_bounds__(256) void frechet_wavefront(
    const float* __restrict__ x,   // [B, 256, 3]
    const float* __restrict__ y,   // [B, 256, 3]
    float* __restrict__ out)       // [B]
{
    const int b = blockIdx.x;
    const int i = threadIdx.x;     // row index, one thread per row

    __shared__ float ybuf[MCOLS * 3];
    __shared__ float buf[3][NROWS];   // rotating anti-diagonal buffers

    // x row i -> registers
    const float x0 = x[(b * NROWS + i) * 3 + 0];
    const float x1 = x[(b * NROWS + i) * 3 + 1];
    const float x2 = x[(b * NROWS + i) * 3 + 2];

    // stage y for this batch into LDS (768 floats)
    for (int t = i; t < MCOLS * 3; t += NROWS)
        ybuf[t] = y[b * MCOLS * 3 + t];
    __syncthreads();

    const float INF = __builtin_inff();
    float last = 0.0f;

    for (int k = 0; k < NROWS + MCOLS - 1; ++k) {
        float*       cur      = buf[k % 3];
        const float* prev     = buf[(k + 2) % 3];  // diagonal k-1
        const float* prevprev = buf[(k + 1) % 3];  // diagonal k-2

        const int j = k - i;
        if (j >= 0 && j < MCOLS) {
            const float d0 = x0 - ybuf[j * 3 + 0];
            const float d1 = x1 - ybuf[j * 3 + 1];
            const float d2 = x2 - ybuf[j * 3 + 2];
            const float c  = d0 * d0 + d1 * d1 + d2 * d2;

            const float up   = (i > 0) ? prev[i - 1] : INF;
            const float left = (j > 0) ? prev[i]     : INF;
            float dg;
            if (i > 0 && j > 0)      dg = prevprev[i - 1];
            else if (i == 0 && j == 0) dg = 0.0f;     // D[0][0] seed
            else                     dg = INF;

            const float val = fmaxf(c, fminf(fminf(up, left), dg));
            cur[i] = val;
            last = val;
        }
        __syncthreads();
    }

    if (i == NROWS - 1)
        out[b] = last;   // cell (255, 255), computed at k = 510
}

extern "C" void kernel_launch(void* const* d_in, const int* in_sizes, int n_in,
                              void* d_out, int out_size, void* d_ws, size_t ws_size,
                              hipStream_t stream) {
    const float* x = (const float*)d_in[0];
    const float* y = (const float*)d_in[1];
    float* out = (float*)d_out;

    const int B = in_sizes[0] / (NROWS * 3);   // 128
    frechet_wavefront<<<B, NROWS, 0, stream>>>(x, y, out);
}

// Round 2
// 44.734 us; speedup vs baseline: 2.4817x; 2.4817x over previous
//
#include <hip/hip_runtime.h>

#define N 256
#define LANES 64
#define STEPS (N + LANES - 1)   // 319

// One wave per batch. Lane t owns rows 4t..4t+3 (in registers).
// Skewed wavefront: at step s, lane t processes column j = s - t for all
// 4 of its rows. Cross-lane dependency (row 4t-1 of lane t-1) travels via
// __shfl_up once per step — no barriers, no LDS in the main loop.
__global__ __launch_bounds__(64) void frechet_shfl(
    const float* __restrict__ x,   // [B, 256, 3]
    const float* __restrict__ y,   // [B, 256, 3]
    float* __restrict__ out)       // [B]
{
    const int b = blockIdx.x;
    const int t = threadIdx.x;     // 0..63

    __shared__ float4 ldsY[N];     // {y0, y1, y2, |y|^2}

    // Stage y for this batch: 4 columns per lane.
    for (int c = t; c < N; c += LANES) {
        const float y0 = y[(b * N + c) * 3 + 0];
        const float y1 = y[(b * N + c) * 3 + 1];
        const float y2 = y[(b * N + c) * 3 + 2];
        ldsY[c] = make_float4(y0, y1, y2, y0 * y0 + y1 * y1 + y2 * y2);
    }

    // x rows 4t..4t+3 -> registers, pre-scaled by -2 for the fma expansion:
    // cost = |x|^2 + |y|^2 - 2 x.y
    float xm[4][3], sx[4];
    #pragma unroll
    for (int r = 0; r < 4; ++r) {
        const float a0 = x[(b * N + 4 * t + r) * 3 + 0];
        const float a1 = x[(b * N + 4 * t + r) * 3 + 1];
        const float a2 = x[(b * N + 4 * t + r) * 3 + 2];
        xm[r][0] = -2.0f * a0;
        xm[r][1] = -2.0f * a1;
        xm[r][2] = -2.0f * a2;
        sx[r] = a0 * a0 + a1 * a1 + a2 * a2;
    }
    __syncthreads();   // single wave: cheap; makes ldsY visible

    const float INF = __builtin_inff();
    // lv[r] = D[4t+r][j-1] (previous column, own rows)
    float lv0 = INF, lv1 = INF, lv2 = INF, lv3 = INF;
    // carry = D[4t+3][j_last_processed] — shfl'd up to lane t+1
    float carry = INF;
    // diagv = D[4t-1][j-1] (neighbor bottom row, two columns back in time)
    float diagv = (t == 0) ? 0.0f : INF;   // seeds D[0][0] = max(c00, 0)

    float4 ynext = ldsY[0];   // prefetch for first active column

    for (int s = 0; s < STEPS; ++s) {
        const int j = s - t;

        // neighbor's bottom-row value at column j (computed at step s-1)
        float upv = __shfl_up(carry, 1);
        if (t == 0) upv = INF;

        const float4 yv = ynext;
        int jn = j + 1;
        jn = jn < 0 ? 0 : (jn > N - 1 ? N - 1 : jn);
        ynext = ldsY[jn];   // prefetch next column (latency hidden)

        if (j >= 0 && j < N) {
            const float syy = yv.w;
            const float c0 = fmaf(xm[0][0], yv.x, fmaf(xm[0][1], yv.y, fmaf(xm[0][2], yv.z, sx[0] + syy)));
            const float c1 = fmaf(xm[1][0], yv.x, fmaf(xm[1][1], yv.y, fmaf(xm[1][2], yv.z, sx[1] + syy)));
            const float c2 = fmaf(xm[2][0], yv.x, fmaf(xm[2][1], yv.y, fmaf(xm[2][2], yv.z, sx[2] + syy)));
            const float c3 = fmaf(xm[3][0], yv.x, fmaf(xm[3][1], yv.y, fmaf(xm[3][2], yv.z, sx[3] + syy)));

            // off-chain partial mins (left, diag for each row)
            const float m0 = fminf(lv0, diagv);
            const float m1 = fminf(lv1, lv0);
            const float m2 = fminf(lv2, lv1);
            const float m3 = fminf(lv3, lv2);

            // dependent chain: v0 -> v1 -> v2 -> v3 (2 ops per cell)
            const float v0 = fmaxf(c0, fminf(upv, m0));
            const float v1 = fmaxf(c1, fminf(v0, m1));
            const float v2 = fmaxf(c2, fminf(v1, m2));
            const float v3 = fmaxf(c3, fminf(v2, m3));

            lv0 = v0; lv1 = v1; lv2 = v2; lv3 = v3;
            carry = v3;
        }
        diagv = upv;   // becomes D[4t-1][j-1] for the next step
    }

    if (t == LANES - 1)
        out[b] = carry;   // D[255][255]
}

extern "C" void kernel_launch(void* const* d_in, const int* in_sizes, int n_in,
                              void* d_out, int out_size, void* d_ws, size_t ws_size,
                              hipStream_t stream) {
    const float* x = (const float*)d_in[0];
    const float* y = (const float*)d_in[1];
    float* out = (float*)d_out;

    const int B = in_sizes[0] / (N * 3);   // 128
    frechet_shfl<<<B, LANES, 0, stream>>>(x, y, out);
}

// Round 3
// 33.656 us; speedup vs baseline: 3.2985x; 1.3291x over previous
//
#include <hip/hip_runtime.h>

#define N 256
#define LANES 64
#define NPAIRS 260       // LDS column-pairs (2 float4 = 32 B each)
#define PPAD   64        // front pad, in pairs
#define STEPS  192       // N/2 + LANES - 1 = 191, padded to 192 for unroll-4

// One wave per batch. Lane t owns rows 4t..4t+3 in registers and sweeps
// columns left->right, 2 columns per step, skewed by one pair per lane.
// Cross-lane dep (bottom row of lane t-1) travels via 2x __shfl_up per step.
__global__ __launch_bounds__(64) void frechet_shfl2(
    const float* __restrict__ x,   // [B, 256, 3]
    const float* __restrict__ y,   // [B, 256, 3]
    float* __restrict__ out)       // [B]
{
    const int b = blockIdx.x;
    const int t = threadIdx.x;     // 0..63

    // column-pair u stored at swizzled 32B slot: slot = p ^ ((p>>2)&3).
    // Lane read stride = 1 pair -> lanes 16 apart share a bank group (4-way).
    __shared__ float4 ldsY[2 * NPAIRS];

    // stage y: cols t, t+64, t+128, t+192  ({y0,y1,y2,|y|^2} per col)
    #pragma unroll
    for (int k = 0; k < 4; ++k) {
        const int c = t + 64 * k;
        const float y0 = y[(b * N + c) * 3 + 0];
        const float y1 = y[(b * N + c) * 3 + 1];
        const float y2 = y[(b * N + c) * 3 + 2];
        const int p = PPAD + (c >> 1);
        const int slot = p ^ ((p >> 2) & 3);
        ldsY[2 * slot + (c & 1)] = make_float4(y0, y1, y2, y0*y0 + y1*y1 + y2*y2);
    }

    // x rows 4t..4t+3 -> registers, pre-scaled for cost = |x|^2+|y|^2-2x.y
    float xm0[4], xm1[4], xm2[4], sx[4];
    #pragma unroll
    for (int r = 0; r < 4; ++r) {
        const float a0 = x[(b * N + 4 * t + r) * 3 + 0];
        const float a1 = x[(b * N + 4 * t + r) * 3 + 1];
        const float a2 = x[(b * N + 4 * t + r) * 3 + 2];
        xm0[r] = -2.0f * a0;
        xm1[r] = -2.0f * a1;
        xm2[r] = -2.0f * a2;
        sx[r] = a0 * a0 + a1 * a1 + a2 * a2;
    }
    __syncthreads();

    const float INF = __builtin_inff();
    float lv0 = INF, lv1 = INF, lv2 = INF, lv3 = INF;   // own rows @ col j0-1
    float cb0 = INF, cb1 = INF;                          // bottom row @ last 2 cols
    float diagv = (t == 0) ? 0.0f : INF;                 // neighbor bottom @ j0-1 (seeds D[0][0])

    // prefetch pair for s=0: p = (0 - t) + PPAD
    int p = PPAD - t;
    int slot = p ^ ((p >> 2) & 3);
    float4 ya = ldsY[2 * slot];
    float4 yb = ldsY[2 * slot + 1];

    #pragma unroll 4
    for (int s = 0; s < STEPS; ++s) {
        // neighbor bottom-row values at cols j0, j0+1 (computed last step)
        float u0 = __shfl_up(cb0, 1);
        float u1 = __shfl_up(cb1, 1);
        if (t == 0) { u0 = INF; u1 = INF; }

        const float4 cya = ya, cyb = yb;
        // prefetch next pair (latency hidden across the step)
        p += 1;
        slot = p ^ ((p >> 2) & 3);
        ya = ldsY[2 * slot];
        yb = ldsY[2 * slot + 1];

        if ((unsigned)(s - t) < (unsigned)(N / 2)) {
            const float sa = cya.w, sb = cyb.w;
            const float ca0 = fmaf(xm0[0], cya.x, fmaf(xm1[0], cya.y, fmaf(xm2[0], cya.z, sx[0] + sa)));
            const float ca1 = fmaf(xm0[1], cya.x, fmaf(xm1[1], cya.y, fmaf(xm2[1], cya.z, sx[1] + sa)));
            const float ca2 = fmaf(xm0[2], cya.x, fmaf(xm1[2], cya.y, fmaf(xm2[2], cya.z, sx[2] + sa)));
            const float ca3 = fmaf(xm0[3], cya.x, fmaf(xm1[3], cya.y, fmaf(xm2[3], cya.z, sx[3] + sa)));
            const float cc0 = fmaf(xm0[0], cyb.x, fmaf(xm1[0], cyb.y, fmaf(xm2[0], cyb.z, sx[0] + sb)));
            const float cc1 = fmaf(xm0[1], cyb.x, fmaf(xm1[1], cyb.y, fmaf(xm2[1], cyb.z, sx[1] + sb)));
            const float cc2 = fmaf(xm0[2], cyb.x, fmaf(xm1[2], cyb.y, fmaf(xm2[2], cyb.z, sx[2] + sb)));
            const float cc3 = fmaf(xm0[3], cyb.x, fmaf(xm1[3], cyb.y, fmaf(xm2[3], cyb.z, sx[3] + sb)));

            // column j0 (nested fmin pairs -> v_min3_f32 fusion)
            const float v0 = fmaxf(ca0, fminf(fminf(u0, lv0), diagv));
            const float v1 = fmaxf(ca1, fminf(fminf(v0, lv1), lv0));
            const float v2 = fmaxf(ca2, fminf(fminf(v1, lv2), lv1));
            const float v3 = fmaxf(ca3, fminf(fminf(v2, lv3), lv2));

            // column j0+1: up = u1, left = v_r, diag row0 = u0
            const float w0 = fmaxf(cc0, fminf(fminf(u1, v0), u0));
            const float w1 = fmaxf(cc1, fminf(fminf(w0, v1), v0));
            const float w2 = fmaxf(cc2, fminf(fminf(w1, v2), v1));
            const float w3 = fmaxf(cc3, fminf(fminf(w2, v3), v2));

            lv0 = w0; lv1 = w1; lv2 = w2; lv3 = w3;
            cb0 = v3; cb1 = w3;
        }
        diagv = u1;   // neighbor bottom @ (next j0) - 1
    }

    if (t == LANES - 1)
        out[b] = cb1;   // D[255][255]
}

extern "C" void kernel_launch(void* const* d_in, const int* in_sizes, int n_in,
                              void* d_out, int out_size, void* d_ws, size_t ws_size,
                              hipStream_t stream) {
    const float* x = (const float*)d_in[0];
    const float* y = (const float*)d_in[1];
    float* out = (float*)d_out;

    const int B = in_sizes[0] / (N * 3);   // 128
    frechet_shfl2<<<B, LANES, 0, stream>>>(x, y, out);
}

// Round 9
// 31.333 us; speedup vs baseline: 3.5431x; 1.0741x over previous
//
#include <hip/hip_runtime.h>

#define N 256
#define LANES 64
#define NPAIRS 260       // LDS column-pairs (2 float4 = 32 B each)
#define PPAD   64        // front pad, in pairs
#define STEPS  192       // N/2 + LANES - 1 = 191, padded to 192 for unroll-4

// DPP wave_shr:1 — lane i gets src[i-1]; lane 0 gets `old` (= INF).
// Pure VALU cross-lane: replaces ds_bpermute-based __shfl_up on the
// critical dependency chain (~35 cyc LDS-pipe -> ~4 cyc VALU).
__device__ __forceinline__ float wave_shr1_inf(float v) {
    const int INFBITS = 0x7f800000;
    return __int_as_float(
        __builtin_amdgcn_update_dpp(INFBITS, __float_as_int(v),
                                    0x138 /*wave_shr:1*/, 0xf, 0xf, false));
}

// One wave per batch. Lane t owns rows 4t..4t+3 in registers, sweeps 2
// columns per step, skewed one pair per lane. Cross-lane dep via DPP.
__global__ __launch_bounds__(64) void frechet_dpp(
    const float* __restrict__ x,   // [B, 256, 3]
    const float* __restrict__ y,   // [B, 256, 3]
    float* __restrict__ out)       // [B]
{
    const int b = blockIdx.x;
    const int t = threadIdx.x;     // 0..63

    // column-pair p at swizzled 32B slot: slot = p ^ ((p>>2)&3)
    __shared__ float4 ldsY[2 * NPAIRS];

    #pragma unroll
    for (int k = 0; k < 4; ++k) {
        const int c = t + 64 * k;
        const float y0 = y[(b * N + c) * 3 + 0];
        const float y1 = y[(b * N + c) * 3 + 1];
        const float y2 = y[(b * N + c) * 3 + 2];
        const int p = PPAD + (c >> 1);
        const int slot = p ^ ((p >> 2) & 3);
        ldsY[2 * slot + (c & 1)] = make_float4(y0, y1, y2, y0*y0 + y1*y1 + y2*y2);
    }

    // x rows 4t..4t+3 -> registers, pre-scaled: cost = |x|^2 + |y|^2 - 2 x.y
    float xm0[4], xm1[4], xm2[4], sx[4];
    #pragma unroll
    for (int r = 0; r < 4; ++r) {
        const float a0 = x[(b * N + 4 * t + r) * 3 + 0];
        const float a1 = x[(b * N + 4 * t + r) * 3 + 1];
        const float a2 = x[(b * N + 4 * t + r) * 3 + 2];
        xm0[r] = -2.0f * a0;
        xm1[r] = -2.0f * a1;
        xm2[r] = -2.0f * a2;
        sx[r] = a0 * a0 + a1 * a1 + a2 * a2;
    }
    __syncthreads();

    const float INF = __builtin_inff();
    float lv0 = INF, lv1 = INF, lv2 = INF, lv3 = INF;   // own rows @ col j0-1
    float cb0 = INF, cb1 = INF;                          // bottom row @ last 2 cols
    float diagv = (t == 0) ? 0.0f : INF;                 // seeds D[0][0]

    int p = PPAD - t;
    int slot = p ^ ((p >> 2) & 3);
    float4 ya = ldsY[2 * slot];
    float4 yb = ldsY[2 * slot + 1];

    #pragma unroll 4
    for (int s = 0; s < STEPS; ++s) {
        // neighbor bottom-row values at cols j0, j0+1 (computed last step)
        const float u0 = wave_shr1_inf(cb0);
        const float u1 = wave_shr1_inf(cb1);

        const float4 cya = ya, cyb = yb;
        p += 1;
        slot = p ^ ((p >> 2) & 3);
        ya = ldsY[2 * slot];
        yb = ldsY[2 * slot + 1];

        if ((unsigned)(s - t) < (unsigned)(N / 2)) {
            const float sa = cya.w, sb = cyb.w;
            const float ca0 = fmaf(xm0[0], cya.x, fmaf(xm1[0], cya.y, fmaf(xm2[0], cya.z, sx[0] + sa)));
            const float ca1 = fmaf(xm0[1], cya.x, fmaf(xm1[1], cya.y, fmaf(xm2[1], cya.z, sx[1] + sa)));
            const float ca2 = fmaf(xm0[2], cya.x, fmaf(xm1[2], cya.y, fmaf(xm2[2], cya.z, sx[2] + sa)));
            const float ca3 = fmaf(xm0[3], cya.x, fmaf(xm1[3], cya.y, fmaf(xm2[3], cya.z, sx[3] + sa)));
            const float cc0 = fmaf(xm0[0], cyb.x, fmaf(xm1[0], cyb.y, fmaf(xm2[0], cyb.z, sx[0] + sb)));
            const float cc1 = fmaf(xm0[1], cyb.x, fmaf(xm1[1], cyb.y, fmaf(xm2[1], cyb.z, sx[1] + sb)));
            const float cc2 = fmaf(xm0[2], cyb.x, fmaf(xm1[2], cyb.y, fmaf(xm2[2], cyb.z, sx[2] + sb)));
            const float cc3 = fmaf(xm0[3], cyb.x, fmaf(xm1[3], cyb.y, fmaf(xm2[3], cyb.z, sx[3] + sb)));

            // column j0 (nested fmin pairs -> v_min3_f32)
            const float v0 = fmaxf(ca0, fminf(fminf(u0, lv0), diagv));
            const float v1 = fmaxf(ca1, fminf(fminf(v0, lv1), lv0));
            const float v2 = fmaxf(ca2, fminf(fminf(v1, lv2), lv1));
            const float v3 = fmaxf(ca3, fminf(fminf(v2, lv3), lv2));

            // column j0+1: up = u1, left = v_r, diag row0 = u0
            const float w0 = fmaxf(cc0, fminf(fminf(u1, v0), u0));
            const float w1 = fmaxf(cc1, fminf(fminf(w0, v1), v0));
            const float w2 = fmaxf(cc2, fminf(fminf(w1, v2), v1));
            const float w3 = fmaxf(cc3, fminf(fminf(w2, v3), v2));

            lv0 = w0; lv1 = w1; lv2 = w2; lv3 = w3;
            cb0 = v3; cb1 = w3;
        }
        diagv = u1;   // becomes neighbor-bottom @ (next j0) - 1
    }

    if (t == LANES - 1)
        out[b] = cb1;   // D[255][255]
}

extern "C" void kernel_launch(void* const* d_in, const int* in_sizes, int n_in,
                              void* d_out, int out_size, void* d_ws, size_t ws_size,
                              hipStream_t stream) {
    const float* x = (const float*)d_in[0];
    const float* y = (const float*)d_in[1];
    float* out = (float*)d_out;

    const int B = in_sizes[0] / (N * 3);   // 128
    frechet_dpp<<<B, LANES, 0, stream>>>(x, y, out);
}

// Round 10
// 30.723 us; speedup vs baseline: 3.6134x; 1.0199x over previous
//
#include <hip/hip_runtime.h>

#define N 256
#define LANES 64
#define NPAIRS 256       // total LDS column-pairs incl. pads (2 float4 = 32 B each)
#define PPAD   64        // front pad, in pairs; real pairs [64,192); tail pad [192,256)
#define STEPS  191       // lane 63 computes its last real pair (127) at s = 190

// DPP wave_shr:1 — lane i gets src[i-1]; lane 0 gets `old` (= INF).
__device__ __forceinline__ float wave_shr1_inf(float v) {
    const int INFBITS = 0x7f800000;
    return __int_as_float(
        __builtin_amdgcn_update_dpp(INFBITS, __float_as_int(v),
                                    0x138 /*wave_shr:1*/, 0xf, 0xf, false));
}

// One wave per batch. Lane t owns rows 4t..4t+3 in registers, sweeps 2
// columns per step, skewed one pair per lane. Branchless main loop:
// out-of-range pairs read {0,0,0,+INF} pads -> cost=+INF -> cells stay INF,
// which is exactly the DP boundary value. No exec-mask ops, no divergence.
__global__ __launch_bounds__(64) void frechet_dpp_nb(
    const float* __restrict__ x,   // [B, 256, 3]
    const float* __restrict__ y,   // [B, 256, 3]
    float* __restrict__ out)       // [B]
{
    const int b = blockIdx.x;
    const int t = threadIdx.x;     // 0..63

    const float INF = __builtin_inff();

    // column-pair p at swizzled 32B slot: slot = p ^ ((p>>2)&3)  (bijective)
    __shared__ float4 ldsY[2 * NPAIRS];

    // pad init: front pairs [0,64) and tail pairs [192,256), 4 float4/lane
    {
        const float4 padv = make_float4(0.0f, 0.0f, 0.0f, INF);
        const int pf = t;            // front pair
        const int sf = pf ^ ((pf >> 2) & 3);
        ldsY[2 * sf]     = padv;
        ldsY[2 * sf + 1] = padv;
        const int pt = 192 + t;      // tail pair
        const int st = pt ^ ((pt >> 2) & 3);
        ldsY[2 * st]     = padv;
        ldsY[2 * st + 1] = padv;
    }

    // stage real y: cols t, t+64, t+128, t+192 ({y0,y1,y2,|y|^2} per col)
    #pragma unroll
    for (int k = 0; k < 4; ++k) {
        const int c = t + 64 * k;
        const float y0 = y[(b * N + c) * 3 + 0];
        const float y1 = y[(b * N + c) * 3 + 1];
        const float y2 = y[(b * N + c) * 3 + 2];
        const int p = PPAD + (c >> 1);
        const int slot = p ^ ((p >> 2) & 3);
        ldsY[2 * slot + (c & 1)] = make_float4(y0, y1, y2, y0*y0 + y1*y1 + y2*y2);
    }

    // x rows 4t..4t+3 -> registers, pre-scaled: cost = |x|^2 + |y|^2 - 2 x.y
    float xm0[4], xm1[4], xm2[4], sx[4];
    #pragma unroll
    for (int r = 0; r < 4; ++r) {
        const float a0 = x[(b * N + 4 * t + r) * 3 + 0];
        const float a1 = x[(b * N + 4 * t + r) * 3 + 1];
        const float a2 = x[(b * N + 4 * t + r) * 3 + 2];
        xm0[r] = -2.0f * a0;
        xm1[r] = -2.0f * a1;
        xm2[r] = -2.0f * a2;
        sx[r] = a0 * a0 + a1 * a1 + a2 * a2;
    }
    __syncthreads();

    float lv0 = INF, lv1 = INF, lv2 = INF, lv3 = INF;   // own rows @ col j0-1
    float cb0 = INF, cb1 = INF;                          // bottom row @ last 2 cols
    float diagv = (t == 0) ? 0.0f : INF;                 // seeds D[0][0]

    int p = PPAD - t;                                    // in [1, 64], initialized
    int slot = p ^ ((p >> 2) & 3);
    float4 ya = ldsY[2 * slot];
    float4 yb = ldsY[2 * slot + 1];

    #pragma unroll 4
    for (int s = 0; s < STEPS; ++s) {
        // neighbor bottom-row values at cols j0, j0+1 (computed last step)
        const float u0 = wave_shr1_inf(cb0);
        const float u1 = wave_shr1_inf(cb1);

        const float4 cya = ya, cyb = yb;
        p += 1;                                          // max 255: in-bounds pad
        slot = p ^ ((p >> 2) & 3);
        ya = ldsY[2 * slot];
        yb = ldsY[2 * slot + 1];

        const float sa = cya.w, sb = cyb.w;
        const float ca0 = fmaf(xm0[0], cya.x, fmaf(xm1[0], cya.y, fmaf(xm2[0], cya.z, sx[0] + sa)));
        const float ca1 = fmaf(xm0[1], cya.x, fmaf(xm1[1], cya.y, fmaf(xm2[1], cya.z, sx[1] + sa)));
        const float ca2 = fmaf(xm0[2], cya.x, fmaf(xm1[2], cya.y, fmaf(xm2[2], cya.z, sx[2] + sa)));
        const float ca3 = fmaf(xm0[3], cya.x, fmaf(xm1[3], cya.y, fmaf(xm2[3], cya.z, sx[3] + sa)));
        const float cc0 = fmaf(xm0[0], cyb.x, fmaf(xm1[0], cyb.y, fmaf(xm2[0], cyb.z, sx[0] + sb)));
        const float cc1 = fmaf(xm0[1], cyb.x, fmaf(xm1[1], cyb.y, fmaf(xm2[1], cyb.z, sx[1] + sb)));
        const float cc2 = fmaf(xm0[2], cyb.x, fmaf(xm1[2], cyb.y, fmaf(xm2[2], cyb.z, sx[2] + sb)));
        const float cc3 = fmaf(xm0[3], cyb.x, fmaf(xm1[3], cyb.y, fmaf(xm2[3], cyb.z, sx[3] + sb)));

        // column j0 (nested fmin pairs -> v_min3_f32)
        const float v0 = fmaxf(ca0, fminf(fminf(u0, lv0), diagv));
        const float v1 = fmaxf(ca1, fminf(fminf(v0, lv1), lv0));
        const float v2 = fmaxf(ca2, fminf(fminf(v1, lv2), lv1));
        const float v3 = fmaxf(ca3, fminf(fminf(v2, lv3), lv2));

        // column j0+1: up = u1, left = v_r, diag row0 = u0
        const float w0 = fmaxf(cc0, fminf(fminf(u1, v0), u0));
        const float w1 = fmaxf(cc1, fminf(fminf(w0, v1), v0));
        const float w2 = fmaxf(cc2, fminf(fminf(w1, v2), v1));
        const float w3 = fmaxf(cc3, fminf(fminf(w2, v3), v2));

        lv0 = w0; lv1 = w1; lv2 = w2; lv3 = w3;
        cb0 = v3; cb1 = w3;
        diagv = u1;   // becomes neighbor-bottom @ (next j0) - 1
    }

    if (t == LANES - 1)
        out[b] = cb1;   // D[255][255], computed at s = 190
}

extern "C" void kernel_launch(void* const* d_in, const int* in_sizes, int n_in,
                              void* d_out, int out_size, void* d_ws, size_t ws_size,
                              hipStream_t stream) {
    const float* x = (const float*)d_in[0];
    const float* y = (const float*)d_in[1];
    float* out = (float*)d_out;

    const int B = in_sizes[0] / (N * 3);   // 128
    frechet_dpp_nb<<<B, LANES, 0, stream>>>(x, y, out);
}

// Round 11
// 28.116 us; speedup vs baseline: 3.9484x; 1.0927x over previous
//
#include <hip/hip_runtime.h>

#define N 256
#define LANES 64
#define NPAIRS 264       // pairs: front pad [0,64), real [64,192), tail pad [192,264)
#define PPAD   64

// DPP wave_shr:1 — lane i gets src[i-1]; lane 0 gets `old` (= INF).
__device__ __forceinline__ float wave_shr1_inf(float v) {
    const int INFBITS = 0x7f800000;
    return __int_as_float(
        __builtin_amdgcn_update_dpp(INFBITS, __float_as_int(v),
                                    0x138 /*wave_shr:1*/, 0xf, 0xf, false));
}

// One wave per batch, lane t owns rows 4t..4t+3, 2 columns (1 pair) per step,
// branchless via {0,0,0,+INF} pads. Explicit 2-deep double-buffered prefetch:
// buffers A/B each hold one pair; 4 ds_read_b128 in flight in steady state so
// each load has a full step (~2x its latency) before its consumption wait.
__global__ __launch_bounds__(64) void frechet_db(
    const float* __restrict__ x,   // [B, 256, 3]
    const float* __restrict__ y,   // [B, 256, 3]
    float* __restrict__ out)       // [B]
{
    const int b = blockIdx.x;
    const int t = threadIdx.x;     // 0..63

    const float INF = __builtin_inff();

    __shared__ float4 ldsY[2 * NPAIRS];   // pair p at swizzled slot p^((p>>2)&3)

    // pads: front [0,64), tail [192,264)
    {
        const float4 padv = make_float4(0.0f, 0.0f, 0.0f, INF);
        const int pf = t;
        const int sf = pf ^ ((pf >> 2) & 3);
        ldsY[2 * sf]     = padv;
        ldsY[2 * sf + 1] = padv;
        for (int pp = 192 + t; pp < NPAIRS; pp += 64) {
            const int st = pp ^ ((pp >> 2) & 3);
            ldsY[2 * st]     = padv;
            ldsY[2 * st + 1] = padv;
        }
    }

    // stage real y: cols t, t+64, t+128, t+192 ({y0,y1,y2,|y|^2})
    #pragma unroll
    for (int k = 0; k < 4; ++k) {
        const int c = t + 64 * k;
        const float y0 = y[(b * N + c) * 3 + 0];
        const float y1 = y[(b * N + c) * 3 + 1];
        const float y2 = y[(b * N + c) * 3 + 2];
        const int p = PPAD + (c >> 1);
        const int slot = p ^ ((p >> 2) & 3);
        ldsY[2 * slot + (c & 1)] = make_float4(y0, y1, y2, y0*y0 + y1*y1 + y2*y2);
    }

    // x rows 4t..4t+3, pre-scaled: cost = |x|^2 + |y|^2 - 2 x.y
    float xm0[4], xm1[4], xm2[4], sx[4];
    #pragma unroll
    for (int r = 0; r < 4; ++r) {
        const float a0 = x[(b * N + 4 * t + r) * 3 + 0];
        const float a1 = x[(b * N + 4 * t + r) * 3 + 1];
        const float a2 = x[(b * N + 4 * t + r) * 3 + 2];
        xm0[r] = -2.0f * a0;
        xm1[r] = -2.0f * a1;
        xm2[r] = -2.0f * a2;
        sx[r] = a0 * a0 + a1 * a1 + a2 * a2;
    }
    __syncthreads();

    float lv0 = INF, lv1 = INF, lv2 = INF, lv3 = INF;
    float cb0 = INF, cb1 = INF;
    float diagv = (t == 0) ? 0.0f : INF;   // seeds D[0][0]

    // one DP step consuming pair (q0, q1)
    #define STEP(q0, q1)                                                          \
    {                                                                             \
        const float u0 = wave_shr1_inf(cb0);                                      \
        const float u1 = wave_shr1_inf(cb1);                                      \
        const float sa = (q0).w, sb = (q1).w;                                     \
        const float ca0 = fmaf(xm0[0], (q0).x, fmaf(xm1[0], (q0).y, fmaf(xm2[0], (q0).z, sx[0] + sa))); \
        const float ca1 = fmaf(xm0[1], (q0).x, fmaf(xm1[1], (q0).y, fmaf(xm2[1], (q0).z, sx[1] + sa))); \
        const float ca2 = fmaf(xm0[2], (q0).x, fmaf(xm1[2], (q0).y, fmaf(xm2[2], (q0).z, sx[2] + sa))); \
        const float ca3 = fmaf(xm0[3], (q0).x, fmaf(xm1[3], (q0).y, fmaf(xm2[3], (q0).z, sx[3] + sa))); \
        const float cc0 = fmaf(xm0[0], (q1).x, fmaf(xm1[0], (q1).y, fmaf(xm2[0], (q1).z, sx[0] + sb))); \
        const float cc1 = fmaf(xm0[1], (q1).x, fmaf(xm1[1], (q1).y, fmaf(xm2[1], (q1).z, sx[1] + sb))); \
        const float cc2 = fmaf(xm0[2], (q1).x, fmaf(xm1[2], (q1).y, fmaf(xm2[2], (q1).z, sx[2] + sb))); \
        const float cc3 = fmaf(xm0[3], (q1).x, fmaf(xm1[3], (q1).y, fmaf(xm2[3], (q1).z, sx[3] + sb))); \
        const float v0 = fmaxf(ca0, fminf(fminf(u0, lv0), diagv));                \
        const float v1 = fmaxf(ca1, fminf(fminf(v0, lv1), lv0));                  \
        const float v2 = fmaxf(ca2, fminf(fminf(v1, lv2), lv1));                  \
        const float v3 = fmaxf(ca3, fminf(fminf(v2, lv3), lv2));                  \
        const float w0 = fmaxf(cc0, fminf(fminf(u1, v0), u0));                    \
        const float w1 = fmaxf(cc1, fminf(fminf(w0, v1), v0));                    \
        const float w2 = fmaxf(cc2, fminf(fminf(w1, v2), v1));                    \
        const float w3 = fmaxf(cc3, fminf(fminf(w2, v3), v2));                    \
        lv0 = w0; lv1 = w1; lv2 = w2; lv3 = w3;                                   \
        cb0 = v3; cb1 = w3;                                                       \
        diagv = u1;                                                               \
    }

    // prologue: A <- pair(step 0), B <- pair(step 1)
    int pA = PPAD - t;         // in [1, 64]
    int pB = pA + 1;
    float4 yA0, yA1, yB0, yB1;
    {
        const int sA = pA ^ ((pA >> 2) & 3);
        yA0 = ldsY[2 * sA]; yA1 = ldsY[2 * sA + 1];
        const int sB = pB ^ ((pB >> 2) & 3);
        yB0 = ldsY[2 * sB]; yB1 = ldsY[2 * sB + 1];
    }
    pA += 2; pB += 2;

    // steps 0..189 as 95 double-iterations; epilogue = step 190
    #pragma unroll 1
    for (int k = 0; k < 95; ++k) {
        STEP(yA0, yA1);                       // even step: consume A
        {                                     // reload A for step +2
            const int sA = pA ^ ((pA >> 2) & 3);
            yA0 = ldsY[2 * sA]; yA1 = ldsY[2 * sA + 1];
            pA += 2;
        }
        STEP(yB0, yB1);                       // odd step: consume B
        {                                     // reload B for step +2
            const int sB = pB ^ ((pB >> 2) & 3);
            yB0 = ldsY[2 * sB]; yB1 = ldsY[2 * sB + 1];
            pB += 2;
        }
    }
    STEP(yA0, yA1);                           // step 190

    #undef STEP

    if (t == LANES - 1)
        out[b] = cb1;   // D[255][255]
}

extern "C" void kernel_launch(void* const* d_in, const int* in_sizes, int n_in,
                              void* d_out, int out_size, void* d_ws, size_t ws_size,
                              hipStream_t stream) {
    const float* x = (const float*)d_in[0];
    const float* y = (const float*)d_in[1];
    float* out = (float*)d_out;

    const int B = in_sizes[0] / (N * 3);   // 128
    frechet_db<<<B, LANES, 0, stream>>>(x, y, out);
}